// Round 5
// baseline (99.056 us; speedup 1.0000x reference)
//
#include <hip/hip_runtime.h>
#include <math.h>

#define NS 2000
#define NPAD 2048
#define EPS_F 1.1920928955078125e-07f
#define BLOCK 256
#define WAVES (BLOCK / 64)        // 4 waves per block
#define EPW 16                    // elements per wave (table regs amortized)
#define LOG2E 1.4426950408889634f

// 2^x via v_exp_f32 (named wrapper: __exp2f collides with glibc math.h).
__device__ __forceinline__ float exp2_hw(float x) {
    return __builtin_amdgcn_exp2f(x);
}

// Kernel 1: build two table views in workspace.
//   tabT: transposed pairs. float4 slot (kk*64 + l) holds points 32l+2kk and
//         32l+2kk+1 as (a0, lw0, a1, lw1) -> per-lane register table.
//   tab2: linear float2 (a, lw) -> cooperative chunk re-eval + epilogue (LDS).
// a = atanh-table value, lw = log2(1/(1-x^2)); pads get lw=-1000 => q=0.
__global__ void build_table(float2* __restrict__ tabT, float2* __restrict__ tab2) {
    int i = blockIdx.x * blockDim.x + threadIdx.x;
    if (i >= NPAD) return;
    float a = 0.0f, lw = -1000.0f;
    if (i < NS) {
        const double y0 = -0.9999, y1 = 0.9999;
        const double step = (y1 - y0) / 1999.0;
        float x = (i == NS - 1) ? (float)y1 : (float)(y0 + (double)i * step);
        float ratio = (1.0f + x) / (1.0f - x) + EPS_F;   // ref: (1+x)/(1-x)+EPS
        a = 0.5f * logf(ratio);                          // atanh_x
        float w = 1.0f / (1.0f - x * x);                 // 1/(1-x^2), >= 1
        lw = log2f(w);
    }
    tab2[i] = make_float2(a, lw);
    int l = i >> 5, k = i & 31, kk = k >> 1, h = k & 1;
    tabT[(kk * 64 + l) * 2 + h] = make_float2(a, lw);
}

// Kernel 2: each wave owns EPW consecutive elements. The transposed table
// lives in 64 VGPRs per lane (loaded once from global, reused EPW times) --
// this removes the 16 ds_read_b128/element that made round 4 LDS-pipe-bound.
// Only the selection phase touches LDS (2 reads/element, conflict-free).
__global__ __launch_bounds__(BLOCK) void sample_kernel(
    const float* __restrict__ mean, const float* __restrict__ stdv,
    const float* __restrict__ uni, const float4* __restrict__ gT,
    const float4* __restrict__ gP,
    float* __restrict__ out_vals, float* __restrict__ out_probs, int nElem) {
    __shared__ float4 sPbuf[NPAD / 2];  // linear table view (16 KB)
    const float2* sP = (const float2*)sPbuf;
    for (int t = threadIdx.x; t < NPAD / 2; t += BLOCK) sPbuf[t] = gP[t];
    __syncthreads();

    const int lane = threadIdx.x & 63;
    const int wid = __builtin_amdgcn_readfirstlane(threadIdx.x >> 6);
    const int elemBase = (blockIdx.x * WAVES + wid) * EPW;
    if (elemBase >= nElem) return;

    // Per-lane register table: points 32*lane + [0,32).
    float4 T[16];
    #pragma unroll
    for (int kk = 0; kk < 16; kk++) T[kk] = gT[kk * 64 + lane];

    #pragma unroll 2
    for (int e = 0; e < EPW; e++) {
        const int elem = elemBase + e;               // wave-uniform (SGPR)
        const float mu = mean[elem];
        const float sg = stdv[elem] + EPS_F;         // ref: std + EPS
        const float u = uni[elem];
        const float sg2 = sg * sg;
        const float rden2 = LOG2E / (-2.0f * sg2);   // exp(x)=exp2(x*log2e)
        const float normc = 1.0f / sqrtf(6.2831853071795864f * sg2);

        // Pass 1: per-lane sum of q_i = exp2((a-mu)^2*rden2 + lw), index order.
        float s = 0.0f;
        #pragma unroll
        for (int kk = 0; kk < 16; kk++) {
            float4 v = T[kk];
            float d0 = v.x - mu;
            s += exp2_hw(fmaf(d0 * d0, rden2, v.y));
            float d1 = v.z - mu;
            s += exp2_hw(fmaf(d1 * d1, rden2, v.w));
        }

        // Inclusive wave scan of lane sums.
        float incl = s;
        #pragma unroll
        for (int o = 1; o < 64; o <<= 1) {
            float t2 = __shfl_up(incl, o, 64);
            if (lane >= o) incl += t2;
        }
        const float S = __shfl(incl, 63, 64);        // wave-uniform q-sum
        const float denom = S * normc + EPS_F;       // ref: sum(probs)+EPS
        const float tt = (u * denom) / normc;        // threshold in q-space

        // Crossing lane: first lane whose inclusive sum exceeds tt.
        unsigned long long mgt = __ballot(incl > tt);
        int jstar = mgt ? __builtin_ctzll(mgt) : 64;

        // Cooperative re-eval of chunk jstar (one point per lane, both
        // 32-lane halves duplicate). Linear LDS table: broadcast, no conflict.
        int jj = (jstar < 64) ? jstar : 0;
        float exclb = __shfl(incl - s, jj, 64);      // exclusive offset
        int c = lane & 31;
        float2 al = sP[jj * 32 + c];
        float d = al.x - mu;
        float cum = exp2_hw(fmaf(d * d, rden2, al.y));
        #pragma unroll
        for (int o = 1; o < 32; o <<= 1) {
            float t2 = __shfl_up(cum, o, 32);
            if (c >= o) cum += t2;
        }
        cum += exclb;
        unsigned int m2 = (unsigned int)(__ballot(cum > tt) & 0xffffffffULL);
        int sub = m2 ? (int)__builtin_ctz(m2) : 32;
        int idx = (jstar >= 64) ? 0 : min(jstar * 32 + sub, NS - 1);

        if (lane == 0) {
            float2 al2 = sP[idx];
            float dd = al2.x - mu;
            float pk = exp2_hw(fmaf(dd * dd, rden2, al2.y)) * normc;
            const double y0 = -0.9999, y1 = 0.9999;
            const double step = (y1 - y0) / 1999.0;
            float gv = (idx == NS - 1) ? (float)y1
                                       : (float)(y0 + (double)idx * step);
            out_vals[elem] = gv;
            out_probs[elem] = pk / denom;            // ref: probs/(sum+EPS)
        }
    }
}

extern "C" void kernel_launch(void* const* d_in, const int* in_sizes, int n_in,
                              void* d_out, int out_size, void* d_ws, size_t ws_size,
                              hipStream_t stream) {
    const float* mean = (const float*)d_in[0];
    const float* stdv = (const float*)d_in[1];
    const float* uni = (const float*)d_in[2];
    float* out = (float*)d_out;
    const int nElem = in_sizes[0];                   // 4096*16 = 65536
    float* out_vals = out;
    float* out_probs = out + nElem;

    float2* tabT = (float2*)d_ws;                    // 2048 float2 = 16 KB
    float2* tab2 = tabT + NPAD;                      // 2048 float2 = 16 KB

    build_table<<<NPAD / 256, 256, 0, stream>>>(tabT, tab2);

    const int elemsPerBlock = WAVES * EPW;           // 64
    const int grid = (nElem + elemsPerBlock - 1) / elemsPerBlock;
    sample_kernel<<<grid, BLOCK, 0, stream>>>(mean, stdv, uni,
                                              (const float4*)tabT,
                                              (const float4*)tab2,
                                              out_vals, out_probs, nElem);
}

// Round 6
// 97.992 us; speedup vs baseline: 1.0109x; 1.0109x over previous
//
#include <hip/hip_runtime.h>
#include <math.h>

#define NS 2000
#define NPAD 2048
#define EPS_F 1.1920928955078125e-07f
#define BLOCK 256
#define WAVES (BLOCK / 64)        // 4 waves per block
#define EPW 16                    // elements per wave (table regs amortized)
#define LOG2E 1.4426950408889634f

// 2^x via v_exp_f32 (named wrapper: __exp2f collides with glibc math.h).
__device__ __forceinline__ float exp2_hw(float x) {
    return __builtin_amdgcn_exp2f(x);
}

// Kernel 1: build two table views in workspace.
//   tabT: transposed pairs. float4 slot (kk*64 + l) holds points 32l+2kk and
//         32l+2kk+1 as (a0, lw0, a1, lw1) -> per-lane register table.
//   tab2: linear float2 (a, lw) -> cooperative chunk re-eval + epilogue (LDS).
// a = atanh-table value, lw = log2(1/(1-x^2)); pads get lw=-1000 => q=0.
__global__ void build_table(float2* __restrict__ tabT, float2* __restrict__ tab2) {
    int i = blockIdx.x * blockDim.x + threadIdx.x;
    if (i >= NPAD) return;
    float a = 0.0f, lw = -1000.0f;
    if (i < NS) {
        const double y0 = -0.9999, y1 = 0.9999;
        const double step = (y1 - y0) / 1999.0;
        float x = (i == NS - 1) ? (float)y1 : (float)(y0 + (double)i * step);
        float ratio = (1.0f + x) / (1.0f - x) + EPS_F;   // ref: (1+x)/(1-x)+EPS
        a = 0.5f * logf(ratio);                          // atanh_x
        float w = 1.0f / (1.0f - x * x);                 // 1/(1-x^2), >= 1
        lw = log2f(w);
    }
    tab2[i] = make_float2(a, lw);
    int l = i >> 5, k = i & 31, kk = k >> 1, h = k & 1;
    tabT[(kk * 64 + l) * 2 + h] = make_float2(a, lw);
}

// Kernel 2: each wave owns EPW consecutive elements. The transposed table
// lives in 64 VGPRs per lane, loaded ONCE from global and reused EPW times.
// __launch_bounds__(256,2) lifts the VGPR cap so the compiler cannot
// rematerialize the table loads (round-5 failure: VGPR capped at 48 ->
// table reloaded per element from global, latency-bound).
__global__ __launch_bounds__(BLOCK, 2) void sample_kernel(
    const float* __restrict__ mean, const float* __restrict__ stdv,
    const float* __restrict__ uni, const float4* __restrict__ gT,
    const float4* __restrict__ gP,
    float* __restrict__ out_vals, float* __restrict__ out_probs, int nElem) {
    const int lane = threadIdx.x & 63;

    // Issue the per-lane register-table loads FIRST (latency hides under
    // the LDS fill + barrier). Points 32*lane + [0,32).
    float4 T[16];
    #pragma unroll
    for (int kk = 0; kk < 16; kk++) T[kk] = gT[kk * 64 + lane];

    __shared__ float4 sPbuf[NPAD / 2];  // linear table view (16 KB)
    const float2* sP = (const float2*)sPbuf;
    for (int t = threadIdx.x; t < NPAD / 2; t += BLOCK) sPbuf[t] = gP[t];
    __syncthreads();

    const int wid = __builtin_amdgcn_readfirstlane(threadIdx.x >> 6);
    const int elemBase = (blockIdx.x * WAVES + wid) * EPW;
    if (elemBase >= nElem) return;

    #pragma unroll 1
    for (int e = 0; e < EPW; e++) {
        const int elem = elemBase + e;               // wave-uniform (SGPR)
        const float mu = mean[elem];
        const float sg = stdv[elem] + EPS_F;         // ref: std + EPS
        const float u = uni[elem];
        const float sg2 = sg * sg;
        const float rden2 = LOG2E / (-2.0f * sg2);   // exp(x)=exp2(x*log2e)
        const float normc = 1.0f / sqrtf(6.2831853071795864f * sg2);

        // Pass 1: per-lane sum of q_i = exp2((a-mu)^2*rden2 + lw).
        // Two accumulators break the serial add chain.
        float s0 = 0.0f, s1 = 0.0f;
        #pragma unroll
        for (int kk = 0; kk < 16; kk++) {
            float4 v = T[kk];
            float d0 = v.x - mu;
            s0 += exp2_hw(fmaf(d0 * d0, rden2, v.y));
            float d1 = v.z - mu;
            s1 += exp2_hw(fmaf(d1 * d1, rden2, v.w));
        }
        float s = s0 + s1;

        // Inclusive wave scan of lane sums.
        float incl = s;
        #pragma unroll
        for (int o = 1; o < 64; o <<= 1) {
            float t2 = __shfl_up(incl, o, 64);
            if (lane >= o) incl += t2;
        }
        const float S = __shfl(incl, 63, 64);        // wave-uniform q-sum
        const float denom = S * normc + EPS_F;       // ref: sum(probs)+EPS
        const float tt = (u * denom) / normc;        // threshold in q-space

        // Crossing lane: first lane whose inclusive sum exceeds tt.
        unsigned long long mgt = __ballot(incl > tt);
        int jstar = mgt ? __builtin_ctzll(mgt) : 64;

        // Cooperative re-eval of chunk jstar (one point per lane, both
        // 32-lane halves duplicate). Linear LDS table: broadcast, no conflict.
        int jj = (jstar < 64) ? jstar : 0;
        float exclb = __shfl(incl - s, jj, 64);      // exclusive offset
        int c = lane & 31;
        float2 al = sP[jj * 32 + c];
        float d = al.x - mu;
        float cum = exp2_hw(fmaf(d * d, rden2, al.y));
        #pragma unroll
        for (int o = 1; o < 32; o <<= 1) {
            float t2 = __shfl_up(cum, o, 32);
            if (c >= o) cum += t2;
        }
        cum += exclb;
        unsigned int m2 = (unsigned int)(__ballot(cum > tt) & 0xffffffffULL);
        int sub = m2 ? (int)__builtin_ctz(m2) : 32;
        int idx = (jstar >= 64) ? 0 : min(jstar * 32 + sub, NS - 1);

        if (lane == 0) {
            float2 al2 = sP[idx];
            float dd = al2.x - mu;
            float pk = exp2_hw(fmaf(dd * dd, rden2, al2.y)) * normc;
            const double y0 = -0.9999, y1 = 0.9999;
            const double step = (y1 - y0) / 1999.0;
            float gv = (idx == NS - 1) ? (float)y1
                                       : (float)(y0 + (double)idx * step);
            out_vals[elem] = gv;
            out_probs[elem] = pk / denom;            // ref: probs/(sum+EPS)
        }
    }
}

extern "C" void kernel_launch(void* const* d_in, const int* in_sizes, int n_in,
                              void* d_out, int out_size, void* d_ws, size_t ws_size,
                              hipStream_t stream) {
    const float* mean = (const float*)d_in[0];
    const float* stdv = (const float*)d_in[1];
    const float* uni = (const float*)d_in[2];
    float* out = (float*)d_out;
    const int nElem = in_sizes[0];                   // 4096*16 = 65536
    float* out_vals = out;
    float* out_probs = out + nElem;

    float2* tabT = (float2*)d_ws;                    // 2048 float2 = 16 KB
    float2* tab2 = tabT + NPAD;                      // 2048 float2 = 16 KB

    build_table<<<NPAD / 256, 256, 0, stream>>>(tabT, tab2);

    const int elemsPerBlock = WAVES * EPW;           // 64
    const int grid = (nElem + elemsPerBlock - 1) / elemsPerBlock;
    sample_kernel<<<grid, BLOCK, 0, stream>>>(mean, stdv, uni,
                                              (const float4*)tabT,
                                              (const float4*)tab2,
                                              out_vals, out_probs, nElem);
}

// Round 7
// 95.209 us; speedup vs baseline: 1.0404x; 1.0292x over previous
//
#include <hip/hip_runtime.h>
#include <math.h>

#define NS 2000
#define NPAD 2048
#define EPS_F 1.1920928955078125e-07f
#define BLOCK 256
#define WAVES (BLOCK / 64)        // 4 waves per block
#define EPW 16                    // elements per wave (table regs amortized)
#define LOG2E 1.4426950408889634f

// 2^x via v_exp_f32 (named wrapper: __exp2f collides with glibc math.h).
__device__ __forceinline__ float exp2_hw(float x) {
    return __builtin_amdgcn_exp2f(x);
}

// x += dpp_moved(x): invalid/unselected source lanes contribute 0.
// (old=0, bound_ctrl=1 -> OOB reads 0; row_mask-gated lanes keep old=0.)
template <int CTRL, int RMASK>
__device__ __forceinline__ float dpp_add(float x) {
    int t = __builtin_amdgcn_update_dpp(0, __float_as_int(x), CTRL, RMASK, 0xf, true);
    return x + __int_as_float(t);
}

// Canonical GCN wave64 inclusive add-scan: 6 VALU ops, zero DS-pipe traffic.
__device__ __forceinline__ float scan64(float x) {
    x = dpp_add<0x111, 0xf>(x);   // row_shr:1
    x = dpp_add<0x112, 0xf>(x);   // row_shr:2
    x = dpp_add<0x114, 0xf>(x);   // row_shr:4
    x = dpp_add<0x118, 0xf>(x);   // row_shr:8  -> scan within 16-rows
    x = dpp_add<0x142, 0xa>(x);   // row_bcast:15 -> rows 1,3
    x = dpp_add<0x143, 0xc>(x);   // row_bcast:31 -> rows 2,3
    return x;
}

// Independent inclusive scan within each 32-lane half (coop phase).
__device__ __forceinline__ float scan32(float x) {
    x = dpp_add<0x111, 0xf>(x);
    x = dpp_add<0x112, 0xf>(x);
    x = dpp_add<0x114, 0xf>(x);
    x = dpp_add<0x118, 0xf>(x);
    x = dpp_add<0x142, 0xa>(x);   // row_bcast:15 within each half
    return x;
}

__device__ __forceinline__ float bcast_lane(float x, int lane_sgpr) {
    return __int_as_float(__builtin_amdgcn_readlane(__float_as_int(x), lane_sgpr));
}

// Kernel 1: build two table views in workspace.
//   tabT: transposed pairs. float4 slot (kk*64 + l) holds points 32l+2kk and
//         32l+2kk+1 as (a0, lw0, a1, lw1) -> per-lane register table.
//   tab2: linear float2 (a, lw) -> cooperative chunk re-eval + epilogue (LDS).
// a = atanh-table value, lw = log2(1/(1-x^2)); pads get lw=-1000 => q=0.
__global__ void build_table(float2* __restrict__ tabT, float2* __restrict__ tab2) {
    int i = blockIdx.x * blockDim.x + threadIdx.x;
    if (i >= NPAD) return;
    float a = 0.0f, lw = -1000.0f;
    if (i < NS) {
        const double y0 = -0.9999, y1 = 0.9999;
        const double step = (y1 - y0) / 1999.0;
        float x = (i == NS - 1) ? (float)y1 : (float)(y0 + (double)i * step);
        float ratio = (1.0f + x) / (1.0f - x) + EPS_F;   // ref: (1+x)/(1-x)+EPS
        a = 0.5f * logf(ratio);                          // atanh_x
        float w = 1.0f / (1.0f - x * x);                 // 1/(1-x^2), >= 1
        lw = log2f(w);
    }
    tab2[i] = make_float2(a, lw);
    int l = i >> 5, k = i & 31, kk = k >> 1, h = k & 1;
    tabT[(kk * 64 + l) * 2 + h] = make_float2(a, lw);
}

// Kernel 2: each wave owns EPW consecutive elements. Table lives in 64 VGPRs
// per lane; the opaque asm below makes the loaded values non-rematerializable
// (rounds 5-6: compiler kept VGPR=48 and re-loaded the table per element).
// All scans/broadcasts are DPP/readlane (VALU/SALU) -> DS pipe nearly idle.
__global__ __launch_bounds__(BLOCK, 2) void sample_kernel(
    const float* __restrict__ mean, const float* __restrict__ stdv,
    const float* __restrict__ uni, const float4* __restrict__ gT,
    const float4* __restrict__ gP,
    float* __restrict__ out_vals, float* __restrict__ out_probs, int nElem) {
    const int lane = threadIdx.x & 63;

    // Per-lane register table: points 32*lane + [0,32).
    float4 T[16];
    #pragma unroll
    for (int kk = 0; kk < 16; kk++) T[kk] = gT[kk * 64 + lane];
    // Opaque pass-through: downstream uses see asm results, not loads ->
    // the compiler must keep all 64 VGPRs live instead of re-loading.
    #pragma unroll
    for (int kk = 0; kk < 16; kk++) {
        asm volatile("" : "+v"(T[kk].x), "+v"(T[kk].y),
                          "+v"(T[kk].z), "+v"(T[kk].w));
    }

    __shared__ float4 sPbuf[NPAD / 2];  // linear table view (16 KB)
    const float2* sP = (const float2*)sPbuf;
    for (int t = threadIdx.x; t < NPAD / 2; t += BLOCK) sPbuf[t] = gP[t];
    __syncthreads();

    const int wid = __builtin_amdgcn_readfirstlane(threadIdx.x >> 6);
    const int elemBase = (blockIdx.x * WAVES + wid) * EPW;
    if (elemBase >= nElem) return;

    #pragma unroll 1
    for (int e = 0; e < EPW; e++) {
        const int elem = elemBase + e;               // wave-uniform (SGPR)
        const float mu = mean[elem];
        const float sg = stdv[elem] + EPS_F;         // ref: std + EPS
        const float u = uni[elem];
        const float sg2 = sg * sg;
        const float rden2 = LOG2E / (-2.0f * sg2);   // exp(x)=exp2(x*log2e)
        const float normc = 1.0f / sqrtf(6.2831853071795864f * sg2);

        // Pass 1: per-lane sum of q_i = exp2((a-mu)^2*rden2 + lw).
        float s0 = 0.0f, s1 = 0.0f;
        #pragma unroll
        for (int kk = 0; kk < 16; kk++) {
            float4 v = T[kk];
            float d0 = v.x - mu;
            s0 += exp2_hw(fmaf(d0 * d0, rden2, v.y));
            float d1 = v.z - mu;
            s1 += exp2_hw(fmaf(d1 * d1, rden2, v.w));
        }
        float s = s0 + s1;

        // Wave64 inclusive scan via DPP (VALU-only).
        float incl = scan64(s);
        const float S = bcast_lane(incl, 63);        // wave-uniform q-sum
        const float denom = S * normc + EPS_F;       // ref: sum(probs)+EPS
        const float tt = (u * denom) / normc;        // threshold in q-space

        // Crossing lane: first lane whose inclusive sum exceeds tt.
        unsigned long long mgt = __ballot(incl > tt);
        int jstar = mgt ? __builtin_ctzll(mgt) : 64;
        int jj = (jstar < 64) ? jstar : 0;
        float exclb = bcast_lane(incl - s, jj);      // exclusive offset

        // Cooperative re-eval of chunk jj: one point per lane, both 32-lane
        // halves compute identical copies (LDS broadcast, conflict-free).
        int c = lane & 31;
        float2 al = sP[jj * 32 + c];
        float d = al.x - mu;
        float cum = scan32(exp2_hw(fmaf(d * d, rden2, al.y)));
        cum += exclb;
        unsigned int m2 = (unsigned int)(__ballot(cum > tt) & 0xffffffffULL);
        int sub = m2 ? (int)__builtin_ctz(m2) : 32;
        int idx = (jstar >= 64) ? 0 : min(jj * 32 + sub, NS - 1);

        if (lane == 0) {
            float2 al2 = sP[idx];
            float dd = al2.x - mu;
            float pk = exp2_hw(fmaf(dd * dd, rden2, al2.y)) * normc;
            const double y0 = -0.9999, y1 = 0.9999;
            const double step = (y1 - y0) / 1999.0;
            float gv = (idx == NS - 1) ? (float)y1
                                       : (float)(y0 + (double)idx * step);
            out_vals[elem] = gv;
            out_probs[elem] = pk / denom;            // ref: probs/(sum+EPS)
        }
    }
}

extern "C" void kernel_launch(void* const* d_in, const int* in_sizes, int n_in,
                              void* d_out, int out_size, void* d_ws, size_t ws_size,
                              hipStream_t stream) {
    const float* mean = (const float*)d_in[0];
    const float* stdv = (const float*)d_in[1];
    const float* uni = (const float*)d_in[2];
    float* out = (float*)d_out;
    const int nElem = in_sizes[0];                   // 4096*16 = 65536
    float* out_vals = out;
    float* out_probs = out + nElem;

    float2* tabT = (float2*)d_ws;                    // 2048 float2 = 16 KB
    float2* tab2 = tabT + NPAD;                      // 2048 float2 = 16 KB

    build_table<<<NPAD / 256, 256, 0, stream>>>(tabT, tab2);

    const int elemsPerBlock = WAVES * EPW;           // 64
    const int grid = (nElem + elemsPerBlock - 1) / elemsPerBlock;
    sample_kernel<<<grid, BLOCK, 0, stream>>>(mean, stdv, uni,
                                              (const float4*)tabT,
                                              (const float4*)tab2,
                                              out_vals, out_probs, nElem);
}

// Round 8
// 85.710 us; speedup vs baseline: 1.1557x; 1.1108x over previous
//
#include <hip/hip_runtime.h>
#include <math.h>

#define NS 2000
#define NPAD 2048
#define EPS_F 1.1920928955078125e-07f
#define BLOCK 1024
#define WAVES (BLOCK / 64)        // 16 waves per block, 1 element per wave
#define LOG2E 1.4426950408889634f

// 2^x via v_exp_f32 (named wrapper: __exp2f collides with glibc math.h).
__device__ __forceinline__ float exp2_hw(float x) {
    return __builtin_amdgcn_exp2f(x);
}

// x += dpp_moved(x): old=0, bound_ctrl=1 -> OOB/unselected lanes add 0.
// Verified on HW in round 7 (absmax unchanged vs shfl path).
template <int CTRL, int RMASK>
__device__ __forceinline__ float dpp_add(float x) {
    int t = __builtin_amdgcn_update_dpp(0, __float_as_int(x), CTRL, RMASK, 0xf, true);
    return x + __int_as_float(t);
}

// Wave64 inclusive add-scan: 6 VALU ops, zero DS-pipe traffic.
__device__ __forceinline__ float scan64(float x) {
    x = dpp_add<0x111, 0xf>(x);   // row_shr:1
    x = dpp_add<0x112, 0xf>(x);   // row_shr:2
    x = dpp_add<0x114, 0xf>(x);   // row_shr:4
    x = dpp_add<0x118, 0xf>(x);   // row_shr:8
    x = dpp_add<0x142, 0xa>(x);   // row_bcast:15 -> rows 1,3
    x = dpp_add<0x143, 0xc>(x);   // row_bcast:31 -> rows 2,3
    return x;
}

// Independent inclusive scan within each 32-lane half.
__device__ __forceinline__ float scan32(float x) {
    x = dpp_add<0x111, 0xf>(x);
    x = dpp_add<0x112, 0xf>(x);
    x = dpp_add<0x114, 0xf>(x);
    x = dpp_add<0x118, 0xf>(x);
    x = dpp_add<0x142, 0xa>(x);   // row_bcast:15 within each half
    return x;
}

__device__ __forceinline__ float bcast_lane(float x, int lane_sgpr) {
    return __int_as_float(__builtin_amdgcn_readlane(__float_as_int(x), lane_sgpr));
}

// Kernel 1: build two table views in workspace.
//   tabT: transposed pairs. float4 slot (kk*64 + l) holds points 32l+2kk and
//         32l+2kk+1 as (a0, lw0, a1, lw1) -> pass-1 lane-consecutive b128.
//   tab2: linear float2 (a, lw) -> cooperative chunk re-eval + epilogue.
// a = atanh-table value, lw = log2(1/(1-x^2)); pads get lw=-1000 => q=0.
__global__ void build_table(float2* __restrict__ tabT, float2* __restrict__ tab2) {
    int i = blockIdx.x * blockDim.x + threadIdx.x;
    if (i >= NPAD) return;
    float a = 0.0f, lw = -1000.0f;
    if (i < NS) {
        const double y0 = -0.9999, y1 = 0.9999;
        const double step = (y1 - y0) / 1999.0;
        float x = (i == NS - 1) ? (float)y1 : (float)(y0 + (double)i * step);
        float ratio = (1.0f + x) / (1.0f - x) + EPS_F;   // ref: (1+x)/(1-x)+EPS
        a = 0.5f * logf(ratio);                          // atanh_x
        float w = 1.0f / (1.0f - x * x);                 // 1/(1-x^2), >= 1
        lw = log2f(w);
    }
    tab2[i] = make_float2(a, lw);
    int l = i >> 5, k = i & 31, kk = k >> 1, h = k & 1;
    tabT[(kk * 64 + l) * 2 + h] = make_float2(a, lw);
}

// Kernel 2: ONE wave per element (65536 waves -> full latency hiding, the
// r5-r7 low-occupancy failure mode avoided). Table read from LDS: 16
// ds_read_b128 per element (DS-pipe floor). All scans/broadcasts are
// DPP/readlane (VALU/SALU) -> no ds_bpermute on the shared DS pipe.
__global__ __launch_bounds__(BLOCK) void sample_kernel(
    const float* __restrict__ mean, const float* __restrict__ stdv,
    const float* __restrict__ uni, const float4* __restrict__ gT,
    const float4* __restrict__ gP,
    float* __restrict__ out_vals, float* __restrict__ out_probs, int nElem) {
    __shared__ float4 sT[NPAD / 2];     // transposed pair view (16 KB)
    __shared__ float4 sPbuf[NPAD / 2];  // linear view (16 KB)
    const float2* sP = (const float2*)sPbuf;
    {
        int t = threadIdx.x;            // 0..1023 == NPAD/2-1
        sT[t] = gT[t];
        sPbuf[t] = gP[t];
    }
    __syncthreads();

    const int lane = threadIdx.x & 63;
    const int wid = threadIdx.x >> 6;
    const int elem = blockIdx.x * WAVES + wid;
    if (elem >= nElem) return;

    const float mu = mean[elem];
    const float sg = stdv[elem] + EPS_F;               // ref: std + EPS
    const float u = uni[elem];
    const float sg2 = sg * sg;
    const float rden2 = LOG2E / (-2.0f * sg2);         // exp(x)=exp2(x*log2e)
    const float normc = 1.0f / sqrtf(6.2831853071795864f * sg2);

    // Pass 1: per-lane sum of q_i = exp2((a-mu)^2*rden2 + lw), index order.
    // Lane l owns points [32l, 32l+32). Two accumulators break the add chain.
    float s0 = 0.0f, s1 = 0.0f;
    #pragma unroll
    for (int kk = 0; kk < 16; kk++) {
        float4 v = sT[kk * 64 + lane];                 // 2 points, b128
        float d0 = v.x - mu;
        s0 += exp2_hw(fmaf(d0 * d0, rden2, v.y));
        float d1 = v.z - mu;
        s1 += exp2_hw(fmaf(d1 * d1, rden2, v.w));
    }
    float s = s0 + s1;

    // Wave64 inclusive scan via DPP (VALU-only).
    float incl = scan64(s);
    const float S = bcast_lane(incl, 63);              // wave-uniform q-sum
    const float denom = S * normc + EPS_F;             // ref: sum(probs)+EPS
    const float tt = (u * denom) / normc;              // threshold in q-space

    // Crossing lane: first lane whose inclusive sum exceeds tt.
    unsigned long long mgt = __ballot(incl > tt);
    int jstar = mgt ? __builtin_ctzll(mgt) : 64;
    int jj = (jstar < 64) ? jstar : 0;
    float exclb = bcast_lane(incl - s, jj);            // exclusive offset

    // Cooperative re-eval of chunk jj: one point per lane, both 32-lane
    // halves duplicate (same-address pairs broadcast, conflict-free).
    int c = lane & 31;
    float2 al = sP[jj * 32 + c];
    float d = al.x - mu;
    float cum = scan32(exp2_hw(fmaf(d * d, rden2, al.y)));
    cum += exclb;
    unsigned int m2 = (unsigned int)(__ballot(cum > tt) & 0xffffffffULL);
    int sub = m2 ? (int)__builtin_ctz(m2) : 32;
    int idx = (jstar >= 64) ? 0 : min(jj * 32 + sub, NS - 1);

    if (lane == 0) {
        float2 al2 = sP[idx];
        float dd = al2.x - mu;
        float pk = exp2_hw(fmaf(dd * dd, rden2, al2.y)) * normc;
        const double y0 = -0.9999, y1 = 0.9999;
        const double step = (y1 - y0) / 1999.0;
        float gv = (idx == NS - 1) ? (float)y1
                                   : (float)(y0 + (double)idx * step);
        out_vals[elem] = gv;
        out_probs[elem] = pk / denom;                  // ref: probs/(sum+EPS)
    }
}

extern "C" void kernel_launch(void* const* d_in, const int* in_sizes, int n_in,
                              void* d_out, int out_size, void* d_ws, size_t ws_size,
                              hipStream_t stream) {
    const float* mean = (const float*)d_in[0];
    const float* stdv = (const float*)d_in[1];
    const float* uni = (const float*)d_in[2];
    float* out = (float*)d_out;
    const int nElem = in_sizes[0];                     // 4096*16 = 65536
    float* out_vals = out;
    float* out_probs = out + nElem;

    float2* tabT = (float2*)d_ws;                      // 2048 float2 = 16 KB
    float2* tab2 = tabT + NPAD;                        // 2048 float2 = 16 KB

    build_table<<<NPAD / 256, 256, 0, stream>>>(tabT, tab2);

    const int grid = (nElem + WAVES - 1) / WAVES;      // 4096 blocks
    sample_kernel<<<grid, BLOCK, 0, stream>>>(mean, stdv, uni,
                                              (const float4*)tabT,
                                              (const float4*)tab2,
                                              out_vals, out_probs, nElem);
}